// Round 2
// baseline (604.241 us; speedup 1.0000x reference)
//
#include <hip/hip_runtime.h>

#define B_ 2
#define S_ 2048
#define D_ 1024
#define H_ 16
#define DK_ 64

typedef __attribute__((ext_vector_type(8))) short vshort8;   // 8 x bf16 (4 VGPRs)
typedef __attribute__((ext_vector_type(4))) float vfloat4;   // MFMA C/D

// f32 -> bf16 round-to-nearest-even (no NaNs in this problem)
static __device__ inline unsigned short f2bf(float f) {
    unsigned int x = __float_as_uint(f);
    x += 0x7fffu + ((x >> 16) & 1u);
    return (unsigned short)(x >> 16);
}
static __device__ inline float bf2f(unsigned short u) {
    return __uint_as_float((unsigned int)u << 16);
}

// ---------------------------------------------------------------------------
// Cast up to 4 f32 tensors to bf16.
// ---------------------------------------------------------------------------
__global__ __launch_bounds__(256) void cast_bf16_kernel(
    const float* s0, const float* s1, const float* s2, const float* s3,
    unsigned short* d0, unsigned short* d1, unsigned short* d2, unsigned short* d3)
{
    int z = blockIdx.z;
    const float* s = (z == 0) ? s0 : (z == 1) ? s1 : (z == 2) ? s2 : s3;
    unsigned short* d = (z == 0) ? d0 : (z == 1) ? d1 : (z == 2) ? d2 : d3;
    int i = (blockIdx.x * 256 + threadIdx.x) * 8;
    float4 f0 = *(const float4*)(s + i);
    float4 f1 = *(const float4*)(s + i + 4);
    uint4 o;
    o.x = (unsigned int)f2bf(f0.x) | ((unsigned int)f2bf(f0.y) << 16);
    o.y = (unsigned int)f2bf(f0.z) | ((unsigned int)f2bf(f0.w) << 16);
    o.z = (unsigned int)f2bf(f1.x) | ((unsigned int)f2bf(f1.y) << 16);
    o.w = (unsigned int)f2bf(f1.z) | ((unsigned int)f2bf(f1.w) << 16);
    *(uint4*)(d + i) = o;
}

// ---------------------------------------------------------------------------
// GEMM: out[M][N] = A[M][K] @ W[N][K]^T + bias, bf16 in.
// mode 0: f32 row-major out. mode 1: bf16 row-major out.
// mode 2: bf16 transposed V^T out, layout (B,H,DK,S) with M=(b,s), N=(h,dk).
// ---------------------------------------------------------------------------
__global__ __launch_bounds__(256) void gemm_bt_kernel(
    const unsigned short* __restrict__ A,
    const unsigned short* __restrict__ Wt,
    const float* __restrict__ bias,
    float* __restrict__ outf,
    unsigned short* __restrict__ outb,
    int M, int N, int K, int mode)
{
    __shared__ unsigned short As[128][40];
    __shared__ unsigned short Ws[128][40];

    const int tid  = threadIdx.x;
    const int wave = tid >> 6;
    const int lane = tid & 63;
    const int l15  = lane & 15;
    const int quad = lane >> 4;
    const int wm   = wave >> 1;
    const int wn   = wave & 1;
    const int m0   = blockIdx.y * 128;
    const int n0   = blockIdx.x * 128;

    vfloat4 acc[4][4];
    for (int rt = 0; rt < 4; rt++)
        for (int ct = 0; ct < 4; ct++) {
            vfloat4 z = {0.f, 0.f, 0.f, 0.f};
            acc[rt][ct] = z;
        }

    const int srow = tid >> 2;
    const int scol = (tid & 3) * 8;

    for (int k0 = 0; k0 < K; k0 += 32) {
        *(uint4*)&As[srow][scol]      = *(const uint4*)&A [(long)(m0 + srow)      * K + k0 + scol];
        *(uint4*)&As[srow + 64][scol] = *(const uint4*)&A [(long)(m0 + srow + 64) * K + k0 + scol];
        *(uint4*)&Ws[srow][scol]      = *(const uint4*)&Wt[(long)(n0 + srow)      * K + k0 + scol];
        *(uint4*)&Ws[srow + 64][scol] = *(const uint4*)&Wt[(long)(n0 + srow + 64) * K + k0 + scol];
        __syncthreads();

        vshort8 af[4], bf[4];
        for (int rt = 0; rt < 4; rt++)
            af[rt] = *(const vshort8*)&As[wm * 64 + rt * 16 + l15][quad * 8];
        for (int ct = 0; ct < 4; ct++)
            bf[ct] = *(const vshort8*)&Ws[wn * 64 + ct * 16 + l15][quad * 8];
        for (int rt = 0; rt < 4; rt++)
            for (int ct = 0; ct < 4; ct++)
                acc[rt][ct] = __builtin_amdgcn_mfma_f32_16x16x32_bf16(af[rt], bf[ct], acc[rt][ct], 0, 0, 0);
        __syncthreads();
    }

    for (int rt = 0; rt < 4; rt++) {
        int row = m0 + wm * 64 + rt * 16 + quad * 4;
        for (int ct = 0; ct < 4; ct++) {
            int col = n0 + wn * 64 + ct * 16 + l15;
            float bvv = bias[col];
            if (mode == 0) {
                for (int r = 0; r < 4; r++)
                    outf[(long)(row + r) * N + col] = acc[rt][ct][r] + bvv;
            } else if (mode == 1) {
                for (int r = 0; r < 4; r++)
                    outb[(long)(row + r) * N + col] = f2bf(acc[rt][ct][r] + bvv);
            } else {
                // V^T: (B,H,DK,S); col -> (h,dk), row -> (b,s); 4 r's = consecutive s
                int h  = col >> 6, dk = col & 63;
                int b  = row >> 11, s = row & (S_ - 1);
                unsigned short pk[4];
                for (int r = 0; r < 4; r++) pk[r] = f2bf(acc[rt][ct][r] + bvv);
                uint2 o;
                o.x = (unsigned int)pk[0] | ((unsigned int)pk[1] << 16);
                o.y = (unsigned int)pk[2] | ((unsigned int)pk[3] << 16);
                *(uint2*)&outb[(((long)(b * H_ + h) * DK_ + dk) * S_) + s] = o;
            }
        }
    }
}

// ---------------------------------------------------------------------------
// RMSNorm + RoPE + (B,S,D)->(B,H,S,DK) relayout, bf16 in/out.
// mode 0 = Q (also * 1/8), mode 1 = K.
// ---------------------------------------------------------------------------
__global__ __launch_bounds__(256) void normrope_kernel(
    const unsigned short* __restrict__ x, // (B*S, D) bf16
    const float* __restrict__ cosb,
    const float* __restrict__ sinb,
    const float* __restrict__ w,
    unsigned short* __restrict__ out,     // (B,H,S,DK) bf16
    int mode)
{
    int wave = threadIdx.x >> 6;
    int lane = threadIdx.x & 63;
    int g = blockIdx.x * 4 + wave;
    int i = g >> 4;
    int h = g & 15;
    int s = i & (S_ - 1);
    int b = i >> 11;

    float v = bf2f(x[(long)i * D_ + h * DK_ + lane]);
    float ss = v * v;
    for (int off = 1; off < 64; off <<= 1) ss += __shfl_xor(ss, off, 64);
    float rn = rsqrtf(ss * (1.0f / 64.0f) + 1e-6f);
    float xn = v * rn * w[lane];
    float other = __shfl_xor(xn, 32, 64);
    float rot = (lane < 32) ? -other : other;
    float val = xn * cosb[s * DK_ + lane] + rot * sinb[s * DK_ + lane];
    if (mode == 0) val *= 0.125f;
    out[((long)(b * H_ + h) * S_ + s) * DK_ + lane] = f2bf(val);
}

// ---------------------------------------------------------------------------
// Causal flash attention, transposed dataflow.
//   S^T = K Q^T  (A=K rows, B=Q rows; C-layout: col=q=l15, row=kv=quad*4+r)
//   O^T = V^T P^T (A=V^T rows, B=P rows)  -> all LDS traffic is b128/b64.
// Block = 256 thr (4 waves), Q-tile 128 (32 q/wave as 2 n-frags), KV-tile 64.
// Softmax row state lives per-lane (q=l15), reduced with 2 shuffles (quads).
// Heavy-first: qq = 15 - blockIdx.x (LPT scheduling of causal imbalance).
// ---------------------------------------------------------------------------
__global__ __launch_bounds__(256) void attn_kernel(
    const unsigned short* __restrict__ Q,   // (B*H, S, DK) bf16, pre-scaled 1/8
    const unsigned short* __restrict__ K,   // (B*H, S, DK) bf16
    const unsigned short* __restrict__ Vt,  // (B*H, DK, S) bf16
    unsigned short* __restrict__ O)         // (B, S, D) bf16
{
    __shared__ unsigned short QP[128][72];  // Q stage, then P^T stage [q][kv]
    __shared__ unsigned short Ks[64][72];
    __shared__ unsigned short Vs[64][72];   // V^T tile [dk][kv]

    const int tid  = threadIdx.x;
    const int wave = tid >> 6;
    const int lane = tid & 63;
    const int l15  = lane & 15;
    const int quad = lane >> 4;
    const int qq   = (gridDim.x - 1) - blockIdx.x;
    const int bh   = blockIdx.y;
    const int b    = bh >> 4;
    const int h    = bh & 15;
    const int q0   = qq * 128;
    const long baseQ = (long)bh * S_ * DK_;
    const long baseV = (long)bh * DK_ * S_;

    // stage Q tile 128x64
    for (int j = 0; j < 4; j++) {
        int c = tid + 256 * j;
        int r = c >> 3, cc = (c & 7) * 8;
        *(uint4*)&QP[r][cc] = *(const uint4*)&Q[baseQ + (long)(q0 + r) * DK_ + cc];
    }
    __syncthreads();
    vshort8 bq[2][2];
    for (int nq = 0; nq < 2; nq++)
        for (int kh = 0; kh < 2; kh++)
            bq[nq][kh] = *(const vshort8*)&QP[wave * 32 + nq * 16 + l15][kh * 32 + quad * 8];

    vfloat4 Oacc[4][2];
    for (int dt = 0; dt < 4; dt++)
        for (int nq = 0; nq < 2; nq++) { vfloat4 z = {0.f,0.f,0.f,0.f}; Oacc[dt][nq] = z; }
    float m_run[2] = {-1e30f, -1e30f};
    float l_run[2] = {0.f, 0.f};

    const int nkt = 2 * qq + 2;
    for (int kt = 0; kt < nkt; kt++) {
        const int k0 = kt * 64;
        {   // stage K (64x64 rows) and V^T (64 dk x 64 kv)
            int r = tid >> 3, cc = (tid & 7) * 8;
            *(uint4*)&Ks[r][cc]      = *(const uint4*)&K [baseQ + (long)(k0 + r)      * DK_ + cc];
            *(uint4*)&Ks[r + 32][cc] = *(const uint4*)&K [baseQ + (long)(k0 + r + 32) * DK_ + cc];
            *(uint4*)&Vs[r][cc]      = *(const uint4*)&Vt[baseV + (long)r        * S_ + k0 + cc];
            *(uint4*)&Vs[r + 32][cc] = *(const uint4*)&Vt[baseV + (long)(r + 32) * S_ + k0 + cc];
        }
        __syncthreads();

        // S^T = K Q^T : per wave 64 kv x 32 q
        vshort8 ak[4][2];
        for (int ct = 0; ct < 4; ct++)
            for (int kh = 0; kh < 2; kh++)
                ak[ct][kh] = *(const vshort8*)&Ks[ct * 16 + l15][kh * 32 + quad * 8];
        vfloat4 sc[2][4];
        for (int nq = 0; nq < 2; nq++)
            for (int ct = 0; ct < 4; ct++) {
                vfloat4 a = {0.f, 0.f, 0.f, 0.f};
                a = __builtin_amdgcn_mfma_f32_16x16x32_bf16(ak[ct][0], bq[nq][0], a, 0, 0, 0);
                a = __builtin_amdgcn_mfma_f32_16x16x32_bf16(ak[ct][1], bq[nq][1], a, 0, 0, 0);
                sc[nq][ct] = a;
            }

        if (kt >= 2 * qq) {   // diagonal region: elementwise causal mask
            for (int nq = 0; nq < 2; nq++) {
                int qg = q0 + wave * 32 + nq * 16 + l15;
                for (int ct = 0; ct < 4; ct++) {
                    int kvb = k0 + ct * 16 + quad * 4;
                    for (int r = 0; r < 4; r++)
                        if (kvb + r > qg) sc[nq][ct][r] = -1e30f;
                }
            }
        }

        // online softmax: each lane owns one q row (16 kv values in-lane)
        for (int nq = 0; nq < 2; nq++) {
            float mt = -1e30f;
            for (int ct = 0; ct < 4; ct++)
                for (int r = 0; r < 4; r++) mt = fmaxf(mt, sc[nq][ct][r]);
            mt = fmaxf(mt, __shfl_xor(mt, 16, 64));
            mt = fmaxf(mt, __shfl_xor(mt, 32, 64));
            float mnew  = fmaxf(m_run[nq], mt);
            float alpha = __expf(m_run[nq] - mnew);
            m_run[nq] = mnew;
            float rs = 0.f;
            int qrow = wave * 32 + nq * 16 + l15;
            for (int ct = 0; ct < 4; ct++) {
                unsigned short pk[4];
                for (int r = 0; r < 4; r++) {
                    float p = __expf(sc[nq][ct][r] - mnew);
                    rs += p;
                    pk[r] = f2bf(p);
                }
                uint2 o;
                o.x = (unsigned int)pk[0] | ((unsigned int)pk[1] << 16);
                o.y = (unsigned int)pk[2] | ((unsigned int)pk[3] << 16);
                *(uint2*)&QP[qrow][ct * 16 + quad * 4] = o;   // P^T write: 4 consecutive kv
            }
            rs += __shfl_xor(rs, 16, 64);
            rs += __shfl_xor(rs, 32, 64);
            l_run[nq] = l_run[nq] * alpha + rs;
            for (int dt = 0; dt < 4; dt++)
                for (int r = 0; r < 4; r++) Oacc[dt][nq][r] *= alpha;
        }
        __syncthreads();   // P visible (QP no longer needed as Q: frags hoisted)

        // O^T += V^T P^T : A = V^T rows, B = P rows
        vshort8 av[4][2], bp[2][2];
        for (int dt = 0; dt < 4; dt++)
            for (int kh = 0; kh < 2; kh++)
                av[dt][kh] = *(const vshort8*)&Vs[dt * 16 + l15][kh * 32 + quad * 8];
        for (int nq = 0; nq < 2; nq++)
            for (int kh = 0; kh < 2; kh++)
                bp[nq][kh] = *(const vshort8*)&QP[wave * 32 + nq * 16 + l15][kh * 32 + quad * 8];
        for (int dt = 0; dt < 4; dt++)
            for (int nq = 0; nq < 2; nq++) {
                Oacc[dt][nq] = __builtin_amdgcn_mfma_f32_16x16x32_bf16(av[dt][0], bp[nq][0], Oacc[dt][nq], 0, 0, 0);
                Oacc[dt][nq] = __builtin_amdgcn_mfma_f32_16x16x32_bf16(av[dt][1], bp[nq][1], Oacc[dt][nq], 0, 0, 0);
            }
        __syncthreads();   // done reading Ks/Vs/QP before next stage
    }

    // epilogue: lane holds col q, rows dk = dt*16+quad*4+r (consecutive)
    for (int nq = 0; nq < 2; nq++) {
        float inv = 1.0f / l_run[nq];
        int qg = q0 + wave * 32 + nq * 16 + l15;
        long rowbase = (long)(b * S_ + qg) * D_ + h * 64;
        for (int dt = 0; dt < 4; dt++) {
            unsigned short pk[4];
            for (int r = 0; r < 4; r++) pk[r] = f2bf(Oacc[dt][nq][r] * inv);
            uint2 o;
            o.x = (unsigned int)pk[0] | ((unsigned int)pk[1] << 16);
            o.y = (unsigned int)pk[2] | ((unsigned int)pk[3] << 16);
            *(uint2*)&O[rowbase + dt * 16 + quad * 4] = o;
        }
    }
}

// ---------------------------------------------------------------------------
extern "C" void kernel_launch(void* const* d_in, const int* in_sizes, int n_in,
                              void* d_out, int out_size, void* d_ws, size_t ws_size,
                              hipStream_t stream) {
    const float* q    = (const float*)d_in[0];
    const float* k    = (const float*)d_in[1];
    const float* v    = (const float*)d_in[2];
    const float* cosb = (const float*)d_in[4];
    const float* sinb = (const float*)d_in[5];
    const float* wq   = (const float*)d_in[6];
    const float* bq   = (const float*)d_in[7];
    const float* wk   = (const float*)d_in[8];
    const float* bk   = (const float*)d_in[9];
    const float* wv   = (const float*)d_in[10];
    const float* bv   = (const float*)d_in[11];
    const float* wo   = (const float*)d_in[12];
    const float* bo   = (const float*)d_in[13];
    const float* qn_w = (const float*)d_in[14];
    const float* kn_w = (const float*)d_in[15];

    const long MB = 1024 * 1024;
    char* ws = (char*)d_ws;
    unsigned short* xq  = (unsigned short*)(ws + 0 * MB);
    unsigned short* xk  = (unsigned short*)(ws + 8 * MB);
    unsigned short* xv  = (unsigned short*)(ws + 16 * MB);
    unsigned short* wqb = (unsigned short*)(ws + 24 * MB);
    unsigned short* wkb = (unsigned short*)(ws + 26 * MB);
    unsigned short* wvb = (unsigned short*)(ws + 28 * MB);
    unsigned short* wob = (unsigned short*)(ws + 30 * MB);
    unsigned short* tmp = (unsigned short*)(ws + 32 * MB); // bf16 (B*S, D)
    unsigned short* Qn  = (unsigned short*)(ws + 40 * MB);
    unsigned short* Kn  = (unsigned short*)(ws + 48 * MB);
    unsigned short* Vtb = (unsigned short*)(ws + 56 * MB); // V^T (B,H,DK,S)
    unsigned short* Ob  = (unsigned short*)(ws + 64 * MB);

    dim3 blk(256);
    cast_bf16_kernel<<<dim3(2048, 1, 3), blk, 0, stream>>>(q, k, v, q, xq, xk, xv, xq);
    cast_bf16_kernel<<<dim3(512, 1, 4), blk, 0, stream>>>(wq, wk, wv, wo, wqb, wkb, wvb, wob);

    dim3 ggrid(8, 32);
    dim3 ngrid(16384);

    gemm_bt_kernel<<<ggrid, blk, 0, stream>>>(xq, wqb, bq, nullptr, tmp, 4096, 1024, 1024, 1);
    normrope_kernel<<<ngrid, blk, 0, stream>>>(tmp, cosb, sinb, qn_w, Qn, 0);
    gemm_bt_kernel<<<ggrid, blk, 0, stream>>>(xk, wkb, bk, nullptr, tmp, 4096, 1024, 1024, 1);
    normrope_kernel<<<ngrid, blk, 0, stream>>>(tmp, cosb, sinb, kn_w, Kn, 1);
    gemm_bt_kernel<<<ggrid, blk, 0, stream>>>(xv, wvb, bv, nullptr, Vtb, 4096, 1024, 1024, 2);

    attn_kernel<<<dim3(16, 32), blk, 0, stream>>>(Qn, Kn, Vtb, Ob);

    gemm_bt_kernel<<<ggrid, blk, 0, stream>>>(Ob, wob, bo, (float*)d_out, nullptr, 4096, 1024, 1024, 0);
}

// Round 3
// 309.727 us; speedup vs baseline: 1.9509x; 1.9509x over previous
//
#include <hip/hip_runtime.h>

#define B_ 2
#define S_ 2048
#define D_ 1024
#define H_ 16
#define DK_ 64

typedef __attribute__((ext_vector_type(8))) short vshort8;   // 8 x bf16 (4 VGPRs)
typedef __attribute__((ext_vector_type(4))) float vfloat4;   // MFMA C/D

// f32 -> bf16 round-to-nearest-even (no NaNs in this problem)
static __device__ inline unsigned short f2bf(float f) {
    unsigned int x = __float_as_uint(f);
    x += 0x7fffu + ((x >> 16) & 1u);
    return (unsigned short)(x >> 16);
}
static __device__ inline float bf2f(unsigned short u) {
    return __uint_as_float((unsigned int)u << 16);
}

// async global->LDS, 16 B per lane. LDS dest is wave-uniform base + lane*16:
// we pass base+lane*16 so readfirstlane(base) + lane*16 lands each lane right.
typedef __attribute__((address_space(1))) const unsigned int as1_uint;
typedef __attribute__((address_space(3))) unsigned int as3_uint;
static __device__ inline void async16(const void* g, void* l) {
    __builtin_amdgcn_global_load_lds((as1_uint*)g, (as3_uint*)l, 16, 0, 0);
}

// ---------------------------------------------------------------------------
// Cast up to 4 f32 tensors to bf16.
// ---------------------------------------------------------------------------
__global__ __launch_bounds__(256) void cast_bf16_kernel(
    const float* s0, const float* s1, const float* s2, const float* s3,
    unsigned short* d0, unsigned short* d1, unsigned short* d2, unsigned short* d3)
{
    int z = blockIdx.z;
    const float* s = (z == 0) ? s0 : (z == 1) ? s1 : (z == 2) ? s2 : s3;
    unsigned short* d = (z == 0) ? d0 : (z == 1) ? d1 : (z == 2) ? d2 : d3;
    int i = (blockIdx.x * 256 + threadIdx.x) * 8;
    float4 f0 = *(const float4*)(s + i);
    float4 f1 = *(const float4*)(s + i + 4);
    uint4 o;
    o.x = (unsigned int)f2bf(f0.x) | ((unsigned int)f2bf(f0.y) << 16);
    o.y = (unsigned int)f2bf(f0.z) | ((unsigned int)f2bf(f0.w) << 16);
    o.z = (unsigned int)f2bf(f1.x) | ((unsigned int)f2bf(f1.y) << 16);
    o.w = (unsigned int)f2bf(f1.z) | ((unsigned int)f2bf(f1.w) << 16);
    *(uint4*)(d + i) = o;
}

// ---------------------------------------------------------------------------
// GEMM: out[M][N] = A[M][K] @ W[N][K]^T + bias. M=4096, N=K=1024 hardcoded.
// blockIdx.z selects one of up to 3 problem instances (QKV fusion -> 3 bl/CU).
// Staging: global_load_lds width=16 into unpadded LDS (m97 pattern), with an
// XOR column-chunk swizzle so the ds_read_b128 fragment reads are 2-way
// (free) instead of 8-way bank conflicts.
// f32out=0: bf16 row-major out. f32out=1: f32 row-major out (slot-0 ptrs).
// ---------------------------------------------------------------------------
__global__ __launch_bounds__(256) void gemm_bt_kernel(
    const unsigned short* __restrict__ A0, const unsigned short* __restrict__ A1, const unsigned short* __restrict__ A2,
    const unsigned short* __restrict__ W0, const unsigned short* __restrict__ W1, const unsigned short* __restrict__ W2,
    const float* __restrict__ bb0, const float* __restrict__ bb1, const float* __restrict__ bb2,
    unsigned short* __restrict__ o0, unsigned short* __restrict__ o1, unsigned short* __restrict__ o2,
    float* __restrict__ of, int f32out)
{
    __shared__ unsigned short As[128][32];   // unpadded: required by global_load_lds
    __shared__ unsigned short Ws[128][32];

    const int z = blockIdx.z;
    const unsigned short* A    = (z == 0) ? A0 : (z == 1) ? A1 : A2;
    const unsigned short* Wt   = (z == 0) ? W0 : (z == 1) ? W1 : W2;
    const float* bias          = (z == 0) ? bb0 : (z == 1) ? bb1 : bb2;
    unsigned short* outb       = (z == 0) ? o0 : (z == 1) ? o1 : o2;

    const int tid  = threadIdx.x;
    const int wave = tid >> 6;
    const int lane = tid & 63;
    const int l15  = lane & 15;
    const int quad = lane >> 4;
    const int wm   = wave >> 1;
    const int wn   = wave & 1;
    const int m0   = blockIdx.y * 128;
    const int n0   = blockIdx.x * 128;

    // staging geometry: chunk = 1024 B = 16 rows x 32 cols(bf16)/4-slot of 16B.
    // wave w stages chunks {2w, 2w+1} of As and Ws.
    const int li  = lane >> 2;                      // row within chunk
    const int lj  = lane & 3;                       // 16B slot
    const int lcc = (lj ^ ((li >> 1) & 3)) * 8;     // swizzled col chunk (elems)
    const int c0  = wave * 2;

    const unsigned short* gA0 = A  + (long)(m0 + c0 * 16      + li) * D_ + lcc;
    const unsigned short* gA1 = A  + (long)(m0 + c0 * 16 + 16 + li) * D_ + lcc;
    const unsigned short* gW0 = Wt + (long)(n0 + c0 * 16      + li) * D_ + lcc;
    const unsigned short* gW1 = Wt + (long)(n0 + c0 * 16 + 16 + li) * D_ + lcc;
    unsigned short* lA0 = (unsigned short*)As + (c0    ) * 512 + lane * 8;
    unsigned short* lA1 = (unsigned short*)As + (c0 + 1) * 512 + lane * 8;
    unsigned short* lW0 = (unsigned short*)Ws + (c0    ) * 512 + lane * 8;
    unsigned short* lW1 = (unsigned short*)Ws + (c0 + 1) * 512 + lane * 8;

    vfloat4 acc[4][4];
    for (int rt = 0; rt < 4; rt++)
        for (int ct = 0; ct < 4; ct++) {
            vfloat4 zz = {0.f, 0.f, 0.f, 0.f};
            acc[rt][ct] = zz;
        }

    // fragment-read swizzle: row = (multiple of 8) + l15, so (row>>1)&3 == (l15>>1)&3
    const int sw = (quad ^ ((l15 >> 1) & 3)) * 8;

    for (int k0 = 0; k0 < 1024; k0 += 32) {
        async16(gA0 + k0, lA0);
        async16(gA1 + k0, lA1);
        async16(gW0 + k0, lW0);
        async16(gW1 + k0, lW1);
        __syncthreads();                 // drains vmcnt -> LDS tiles complete

        vshort8 af[4], bf[4];
        for (int rt = 0; rt < 4; rt++)
            af[rt] = *(const vshort8*)&As[wm * 64 + rt * 16 + l15][sw];
        for (int ct = 0; ct < 4; ct++)
            bf[ct] = *(const vshort8*)&Ws[wn * 64 + ct * 16 + l15][sw];
        for (int rt = 0; rt < 4; rt++)
            for (int ct = 0; ct < 4; ct++)
                acc[rt][ct] = __builtin_amdgcn_mfma_f32_16x16x32_bf16(af[rt], bf[ct], acc[rt][ct], 0, 0, 0);
        __syncthreads();                 // LDS free for next stage
    }

    for (int rt = 0; rt < 4; rt++) {
        int row = m0 + wm * 64 + rt * 16 + quad * 4;
        for (int ct = 0; ct < 4; ct++) {
            int col = n0 + wn * 64 + ct * 16 + l15;
            float bvv = bias[col];
            if (f32out) {
                for (int r = 0; r < 4; r++)
                    of[(long)(row + r) * D_ + col] = acc[rt][ct][r] + bvv;
            } else {
                for (int r = 0; r < 4; r++)
                    outb[(long)(row + r) * D_ + col] = f2bf(acc[rt][ct][r] + bvv);
            }
        }
    }
}

// ---------------------------------------------------------------------------
// RMSNorm + RoPE + (B,S,D)->(B,H,S,DK) relayout, bf16 in/out.
// blockIdx.y: 0 = Q (norm+rope, *1/8), 1 = K (norm+rope).
// ---------------------------------------------------------------------------
__global__ __launch_bounds__(256) void normrope_kernel(
    const unsigned short* __restrict__ xq, const unsigned short* __restrict__ xk,
    const float* __restrict__ cosb, const float* __restrict__ sinb,
    const float* __restrict__ qw, const float* __restrict__ kw,
    unsigned short* __restrict__ Qn, unsigned short* __restrict__ Kn)
{
    int mode = blockIdx.y;
    const unsigned short* x = mode ? xk : xq;
    const float* w          = mode ? kw : qw;
    unsigned short* out     = mode ? Kn : Qn;

    int wave = threadIdx.x >> 6;
    int lane = threadIdx.x & 63;
    int g = blockIdx.x * 4 + wave;
    int i = g >> 4;
    int h = g & 15;
    int s = i & (S_ - 1);
    int b = i >> 11;

    float v = bf2f(x[(long)i * D_ + h * DK_ + lane]);
    float ss = v * v;
    for (int off = 1; off < 64; off <<= 1) ss += __shfl_xor(ss, off, 64);
    float rn = rsqrtf(ss * (1.0f / 64.0f) + 1e-6f);
    float xn = v * rn * w[lane];
    float other = __shfl_xor(xn, 32, 64);
    float rot = (lane < 32) ? -other : other;
    float val = xn * cosb[s * DK_ + lane] + rot * sinb[s * DK_ + lane];
    if (mode == 0) val *= 0.125f;
    out[((long)(b * H_ + h) * S_ + s) * DK_ + lane] = f2bf(val);
}

// ---------------------------------------------------------------------------
// V relayout: (B,S,D) bf16 -> (B,H,DK,S) bf16 via LDS tile (coalesced both ways).
// Grid (S/64, B*H). 16 MB total traffic.
// ---------------------------------------------------------------------------
__global__ __launch_bounds__(256) void transpose_v_kernel(
    const unsigned short* __restrict__ X,
    unsigned short* __restrict__ Vt)
{
    __shared__ unsigned short T[64][72];
    int st = blockIdx.x, bh = blockIdx.y;
    int b = bh >> 4, h = bh & 15;
    int s0 = st * 64;

    for (int it = 0; it < 2; it++) {
        int idx = threadIdx.x + it * 256;
        int r = idx >> 3;
        int c = (idx & 7) * 8;
        *(uint4*)&T[r][c] = *(const uint4*)&X[(long)(b * S_ + s0 + r) * D_ + h * 64 + c];
    }
    __syncthreads();
    for (int it = 0; it < 2; it++) {
        int idx = threadIdx.x + it * 256;
        int dk = idx >> 3;
        int ss = (idx & 7) * 8;
        unsigned short pk[8];
        for (int j = 0; j < 8; j++) pk[j] = T[ss + j][dk];
        *(uint4*)&Vt[((long)(b * H_ + h) * DK_ + dk) * S_ + s0 + ss] = *(uint4*)pk;
    }
}

// ---------------------------------------------------------------------------
// Causal flash attention, transposed dataflow (unchanged from R2 — correct,
// and no longer the top dispatch; revisit with counters next).
// ---------------------------------------------------------------------------
__global__ __launch_bounds__(256) void attn_kernel(
    const unsigned short* __restrict__ Q,   // (B*H, S, DK) bf16, pre-scaled 1/8
    const unsigned short* __restrict__ K,   // (B*H, S, DK) bf16
    const unsigned short* __restrict__ Vt,  // (B*H, DK, S) bf16
    unsigned short* __restrict__ O)         // (B, S, D) bf16
{
    __shared__ unsigned short QP[128][72];  // Q stage, then P^T stage [q][kv]
    __shared__ unsigned short Ks[64][72];
    __shared__ unsigned short Vs[64][72];   // V^T tile [dk][kv]

    const int tid  = threadIdx.x;
    const int wave = tid >> 6;
    const int lane = tid & 63;
    const int l15  = lane & 15;
    const int quad = lane >> 4;
    const int qq   = (gridDim.x - 1) - blockIdx.x;
    const int bh   = blockIdx.y;
    const int b    = bh >> 4;
    const int h    = bh & 15;
    const int q0   = qq * 128;
    const long baseQ = (long)bh * S_ * DK_;
    const long baseV = (long)bh * DK_ * S_;

    for (int j = 0; j < 4; j++) {
        int c = tid + 256 * j;
        int r = c >> 3, cc = (c & 7) * 8;
        *(uint4*)&QP[r][cc] = *(const uint4*)&Q[baseQ + (long)(q0 + r) * DK_ + cc];
    }
    __syncthreads();
    vshort8 bq[2][2];
    for (int nq = 0; nq < 2; nq++)
        for (int kh = 0; kh < 2; kh++)
            bq[nq][kh] = *(const vshort8*)&QP[wave * 32 + nq * 16 + l15][kh * 32 + quad * 8];

    vfloat4 Oacc[4][2];
    for (int dt = 0; dt < 4; dt++)
        for (int nq = 0; nq < 2; nq++) { vfloat4 zz = {0.f,0.f,0.f,0.f}; Oacc[dt][nq] = zz; }
    float m_run[2] = {-1e30f, -1e30f};
    float l_run[2] = {0.f, 0.f};

    const int nkt = 2 * qq + 2;
    for (int kt = 0; kt < nkt; kt++) {
        const int k0 = kt * 64;
        {
            int r = tid >> 3, cc = (tid & 7) * 8;
            *(uint4*)&Ks[r][cc]      = *(const uint4*)&K [baseQ + (long)(k0 + r)      * DK_ + cc];
            *(uint4*)&Ks[r + 32][cc] = *(const uint4*)&K [baseQ + (long)(k0 + r + 32) * DK_ + cc];
            *(uint4*)&Vs[r][cc]      = *(const uint4*)&Vt[baseV + (long)r        * S_ + k0 + cc];
            *(uint4*)&Vs[r + 32][cc] = *(const uint4*)&Vt[baseV + (long)(r + 32) * S_ + k0 + cc];
        }
        __syncthreads();

        vshort8 ak[4][2];
        for (int ct = 0; ct < 4; ct++)
            for (int kh = 0; kh < 2; kh++)
                ak[ct][kh] = *(const vshort8*)&Ks[ct * 16 + l15][kh * 32 + quad * 8];
        vfloat4 sc[2][4];
        for (int nq = 0; nq < 2; nq++)
            for (int ct = 0; ct < 4; ct++) {
                vfloat4 a = {0.f, 0.f, 0.f, 0.f};
                a = __builtin_amdgcn_mfma_f32_16x16x32_bf16(ak[ct][0], bq[nq][0], a, 0, 0, 0);
                a = __builtin_amdgcn_mfma_f32_16x16x32_bf16(ak[ct][1], bq[nq][1], a, 0, 0, 0);
                sc[nq][ct] = a;
            }

        if (kt >= 2 * qq) {
            for (int nq = 0; nq < 2; nq++) {
                int qg = q0 + wave * 32 + nq * 16 + l15;
                for (int ct = 0; ct < 4; ct++) {
                    int kvb = k0 + ct * 16 + quad * 4;
                    for (int r = 0; r < 4; r++)
                        if (kvb + r > qg) sc[nq][ct][r] = -1e30f;
                }
            }
        }

        for (int nq = 0; nq < 2; nq++) {
            float mt = -1e30f;
            for (int ct = 0; ct < 4; ct++)
                for (int r = 0; r < 4; r++) mt = fmaxf(mt, sc[nq][ct][r]);
            mt = fmaxf(mt, __shfl_xor(mt, 16, 64));
            mt = fmaxf(mt, __shfl_xor(mt, 32, 64));
            float mnew  = fmaxf(m_run[nq], mt);
            float alpha = __expf(m_run[nq] - mnew);
            m_run[nq] = mnew;
            float rs = 0.f;
            int qrow = wave * 32 + nq * 16 + l15;
            for (int ct = 0; ct < 4; ct++) {
                unsigned short pk[4];
                for (int r = 0; r < 4; r++) {
                    float p = __expf(sc[nq][ct][r] - mnew);
                    rs += p;
                    pk[r] = f2bf(p);
                }
                uint2 o;
                o.x = (unsigned int)pk[0] | ((unsigned int)pk[1] << 16);
                o.y = (unsigned int)pk[2] | ((unsigned int)pk[3] << 16);
                *(uint2*)&QP[qrow][ct * 16 + quad * 4] = o;
            }
            rs += __shfl_xor(rs, 16, 64);
            rs += __shfl_xor(rs, 32, 64);
            l_run[nq] = l_run[nq] * alpha + rs;
            for (int dt = 0; dt < 4; dt++)
                for (int r = 0; r < 4; r++) Oacc[dt][nq][r] *= alpha;
        }
        __syncthreads();

        vshort8 av[4][2], bp[2][2];
        for (int dt = 0; dt < 4; dt++)
            for (int kh = 0; kh < 2; kh++)
                av[dt][kh] = *(const vshort8*)&Vs[dt * 16 + l15][kh * 32 + quad * 8];
        for (int nq = 0; nq < 2; nq++)
            for (int kh = 0; kh < 2; kh++)
                bp[nq][kh] = *(const vshort8*)&QP[wave * 32 + nq * 16 + l15][kh * 32 + quad * 8];
        for (int dt = 0; dt < 4; dt++)
            for (int nq = 0; nq < 2; nq++) {
                Oacc[dt][nq] = __builtin_amdgcn_mfma_f32_16x16x32_bf16(av[dt][0], bp[nq][0], Oacc[dt][nq], 0, 0, 0);
                Oacc[dt][nq] = __builtin_amdgcn_mfma_f32_16x16x32_bf16(av[dt][1], bp[nq][1], Oacc[dt][nq], 0, 0, 0);
            }
        __syncthreads();
    }

    for (int nq = 0; nq < 2; nq++) {
        float inv = 1.0f / l_run[nq];
        int qg = q0 + wave * 32 + nq * 16 + l15;
        long rowbase = (long)(b * S_ + qg) * D_ + h * 64;
        for (int dt = 0; dt < 4; dt++) {
            unsigned short pk[4];
            for (int r = 0; r < 4; r++) pk[r] = f2bf(Oacc[dt][nq][r] * inv);
            uint2 o;
            o.x = (unsigned int)pk[0] | ((unsigned int)pk[1] << 16);
            o.y = (unsigned int)pk[2] | ((unsigned int)pk[3] << 16);
            *(uint2*)&O[rowbase + dt * 16 + quad * 4] = o;
        }
    }
}

// ---------------------------------------------------------------------------
extern "C" void kernel_launch(void* const* d_in, const int* in_sizes, int n_in,
                              void* d_out, int out_size, void* d_ws, size_t ws_size,
                              hipStream_t stream) {
    const float* q    = (const float*)d_in[0];
    const float* k    = (const float*)d_in[1];
    const float* v    = (const float*)d_in[2];
    const float* cosb = (const float*)d_in[4];
    const float* sinb = (const float*)d_in[5];
    const float* wq   = (const float*)d_in[6];
    const float* bq   = (const float*)d_in[7];
    const float* wk   = (const float*)d_in[8];
    const float* bk   = (const float*)d_in[9];
    const float* wv   = (const float*)d_in[10];
    const float* bv   = (const float*)d_in[11];
    const float* wo   = (const float*)d_in[12];
    const float* bo   = (const float*)d_in[13];
    const float* qn_w = (const float*)d_in[14];
    const float* kn_w = (const float*)d_in[15];

    const long MB = 1024 * 1024;
    char* ws = (char*)d_ws;
    // buffer reuse plan (56 MB total):
    //   [0,8)   xq   -> Qn      [8,16) xk -> Kn     [16,24) xv -> Vtb
    //   [24,32) weights (wqb 24, wkb 26, wvb 28, wob 30)
    //   [32,40) tmpq -> Ob      [40,48) tmpk        [48,56) tmpv
    unsigned short* xq   = (unsigned short*)(ws + 0 * MB);
    unsigned short* xk   = (unsigned short*)(ws + 8 * MB);
    unsigned short* xv   = (unsigned short*)(ws + 16 * MB);
    unsigned short* wqb  = (unsigned short*)(ws + 24 * MB);
    unsigned short* wkb  = (unsigned short*)(ws + 26 * MB);
    unsigned short* wvb  = (unsigned short*)(ws + 28 * MB);
    unsigned short* wob  = (unsigned short*)(ws + 30 * MB);
    unsigned short* tmpq = (unsigned short*)(ws + 32 * MB);
    unsigned short* tmpk = (unsigned short*)(ws + 40 * MB);
    unsigned short* tmpv = (unsigned short*)(ws + 48 * MB);
    unsigned short* Qn   = (unsigned short*)(ws + 0 * MB);
    unsigned short* Kn   = (unsigned short*)(ws + 8 * MB);
    unsigned short* Vtb  = (unsigned short*)(ws + 16 * MB);
    unsigned short* Ob   = (unsigned short*)(ws + 32 * MB);

    dim3 blk(256);
    cast_bf16_kernel<<<dim3(2048, 1, 3), blk, 0, stream>>>(q, k, v, q, xq, xk, xv, xq);
    cast_bf16_kernel<<<dim3(512, 1, 4), blk, 0, stream>>>(wq, wk, wv, wo, wqb, wkb, wvb, wob);

    // fused QKV projection: 768 blocks = 3 blocks/CU
    gemm_bt_kernel<<<dim3(8, 32, 3), blk, 0, stream>>>(
        xq, xk, xv, wqb, wkb, wvb, bq, bk, bv, tmpq, tmpk, tmpv, nullptr, 0);

    normrope_kernel<<<dim3(16384, 2), blk, 0, stream>>>(
        tmpq, tmpk, cosb, sinb, qn_w, kn_w, Qn, Kn);
    transpose_v_kernel<<<dim3(32, 32), blk, 0, stream>>>(tmpv, Vtb);

    attn_kernel<<<dim3(16, 32), blk, 0, stream>>>(Qn, Kn, Vtb, Ob);

    // output projection, f32 out
    gemm_bt_kernel<<<dim3(8, 32, 1), blk, 0, stream>>>(
        Ob, Ob, Ob, wob, wob, wob, bo, bo, bo, nullptr, nullptr, nullptr,
        (float*)d_out, 1);
}